// Round 4
// baseline (920.645 us; speedup 1.0000x reference)
//
#include <hip/hip_runtime.h>

#define NPTS 100000
#define KN 16
#define DIM 3
#define CIN 64
#define CD 16
#define CT 80
#define COUT 128
#define PTS 4
#define EPSV 1e-5f

// ---- prepacked weights (written by prep_kernel every launch; deterministic) ----
__device__ __align__(16) float g_wmt[48 * 256];  // [(ib*256+j)*4+ii] = Wm[j*48+ib*4+ii]
__device__ unsigned g_w2[16];
__device__ unsigned g_cw1[256];
__device__ unsigned g_cw2[256];
__device__ unsigned g_cw3[2][160];
__device__ unsigned g_wf[2][1280];      // Wf row o -> 10 words

__device__ __forceinline__ float sgnf(float x) {
    return (x > 0.f) ? 1.f : ((x < 0.f) ? -1.f : 0.f);
}
__device__ __forceinline__ float clamp1(float x) { return fminf(1.f, fmaxf(-1.f, x)); }
__device__ __forceinline__ unsigned rot16(unsigned w) { return (w >> 16) | (w << 16); }

__device__ __forceinline__ unsigned packrow16(const float* __restrict__ w) {
    unsigned pos = 0, neg = 0;
    #pragma unroll
    for (int k = 0; k < 16; ++k) {
        pos |= (w[k] > 0.f ? 1u : 0u) << k;
        neg |= (w[k] < 0.f ? 1u : 0u) << k;
    }
    return (neg << 16) | pos;
}

// sign float {-1,0,1} from packed word bit k (exact ±1.0f / 0.0f)
__device__ __forceinline__ float bit_sgn(unsigned w, int k) {
    return (float)((int)((w >> k) & 1u) - (int)((w >> (k + 16)) & 1u));
}

// ternary dot of 16-elem packed words
__device__ __forceinline__ int tdot(unsigned a, unsigned wp, unsigned wr) {
    return __popc(a & wp) - __popc(a & wr);
}

__global__ void prep_kernel(const float* __restrict__ Wm, const float* __restrict__ W2,
                            const float* __restrict__ cw1, const float* __restrict__ cw2,
                            const float* __restrict__ cw3, const float* __restrict__ Wf) {
    int b = blockIdx.x, t = threadIdx.x;
    if (b < 48) {
        int ib = b >> 2, ii = b & 3;
        g_wmt[(ib * 256 + t) * 4 + ii] = Wm[t * 48 + b];
    } else if (b == 48) {
        g_cw1[t] = packrow16(cw1 + t * 16);
    } else if (b == 49) {
        g_cw2[t] = packrow16(cw2 + t * 16);
    } else if (b == 50) {
        if (t < 160) { unsigned w = packrow16(cw3 + t * 16); g_cw3[0][t] = w; g_cw3[1][t] = rot16(w); }
        else if (t < 176) { g_w2[t - 160] = packrow16(W2 + (t - 160) * 16); }
    } else {
        if (t < 128) {
            for (int m = 0; m < 10; ++m) {
                unsigned w = packrow16(Wf + t * 160 + m * 16);
                g_wf[0][t * 10 + m] = w; g_wf[1][t * 10 + m] = rot16(w);
            }
        }
    }
}

__global__ __launch_bounds__(256) void bixconv_kernel(
    const float* __restrict__ x, const float* __restrict__ pos, const int* __restrict__ col,
    const float* __restrict__ W1, const float* __restrict__ b1,
    const float* __restrict__ bn1g, const float* __restrict__ bn1b, const float* __restrict__ bn1m, const float* __restrict__ bn1v,
    const float* __restrict__ b2,
    const float* __restrict__ bn2g, const float* __restrict__ bn2b, const float* __restrict__ bn2m, const float* __restrict__ bn2v,
    const float* __restrict__ bm,
    const float* __restrict__ bn3g, const float* __restrict__ bn3b, const float* __restrict__ bn3m, const float* __restrict__ bn3v,
    const float* __restrict__ cb1,
    const float* __restrict__ bn4g, const float* __restrict__ bn4b, const float* __restrict__ bn4m, const float* __restrict__ bn4v,
    const float* __restrict__ cb2,
    const float* __restrict__ bn5g, const float* __restrict__ bn5b, const float* __restrict__ bn5m, const float* __restrict__ bn5v,
    const float* __restrict__ cb3, const float* __restrict__ bf,
    float* __restrict__ out)
{
    __shared__ int sIdx[PTS][KN];
    __shared__ __align__(16) float sPd[PTS][48];
    __shared__ __align__(16) float sXs[PTS][CT][20];   // rows 0..15: h2, rows 16..79: x[col]
    __shared__ __align__(16) float sT[PTS][KN][20];    // T (stage F output)
    __shared__ unsigned sPkH[PTS][16];                 // packed sign(h1) per (p,k)
    __shared__ unsigned sPk1[PTS][16];                 // packed sign(t1)
    __shared__ unsigned sPk2[PTS][16];                 // packed sign(t2)
    __shared__ unsigned sPkXt[PTS][CT];                // packed sign(xt)
    __shared__ float sS1[PTS][160];                    // sign(y) floats
    __shared__ unsigned sPkY[PTS][10];                 // packed sign(y)

    const int tid = threadIdx.x;
    const int lane = tid & 63;
    const int nb = blockIdx.x * PTS;

    // ---- A1: neighbor indices + relative positions ----
    if (tid < PTS * KN) {
        int p = tid >> 4, k = tid & 15;
        int n = nb + p;
        int idx = col[n * KN + k];
        sIdx[p][k] = idx;
        float ax = pos[n * 3 + 0], ay = pos[n * 3 + 1], az = pos[n * 3 + 2];
        sPd[p][k * 3 + 0] = pos[idx * 3 + 0] - ax;
        sPd[p][k * 3 + 1] = pos[idx * 3 + 1] - ay;
        sPd[p][k * 3 + 2] = pos[idx * 3 + 2] - az;
    }
    __syncthreads();

    // ---- A2: gather x[col] into xs rows 16..79 ----
    {
        int p = tid >> 6, c = lane;
        #pragma unroll
        for (int kb = 0; kb < 4; ++kb) {
            float4 v;
            v.x = x[(size_t)sIdx[p][kb * 4 + 0] * CIN + c];
            v.y = x[(size_t)sIdx[p][kb * 4 + 1] * CIN + c];
            v.z = x[(size_t)sIdx[p][kb * 4 + 2] * CIN + c];
            v.w = x[(size_t)sIdx[p][kb * 4 + 3] * CIN + c];
            *(float4*)&sXs[p][CD + c][kb * 4] = v;
        }
    }
    // ---- B: h1 = bn1(hardtanh(pd @ W1^T + b1)); ballot-pack signs -> sPkH ----
    {
        int c = tid & 15, k = tid >> 4;
        float w0 = W1[c * 3 + 0], w1 = W1[c * 3 + 1], w2v = W1[c * 3 + 2];
        float bb = b1[c];
        float s = bn1g[c] * rsqrtf(bn1v[c] + EPSV);
        float tt = bn1b[c] - bn1m[c] * s;
        #pragma unroll
        for (int p = 0; p < PTS; ++p) {
            float z = sPd[p][k * 3 + 0] * w0 + sPd[p][k * 3 + 1] * w1 + sPd[p][k * 3 + 2] * w2v + bb;
            float v = clamp1(z) * s + tt;
            unsigned long long bp = __ballot(v > 0.f);
            unsigned long long bn_ = __ballot(v < 0.f);
            if ((lane & 15) == 0) {
                unsigned sh = lane & 48;
                sPkH[p][k] = ((unsigned)((bn_ >> sh) & 0xFFFFull) << 16) |
                              (unsigned)((bp >> sh) & 0xFFFFull);
            }
        }
    }
    __syncthreads();

    // ---- C: h2 = bn2(hardtanh(sign(h1).sign(W2))) -> sXs rows 0..15 (exact r1 chain) ----
    {
        int c = tid & 15, k = tid >> 4;
        unsigned wpk = g_w2[c];
        float wsg[16];
        #pragma unroll
        for (int j = 0; j < 16; ++j) wsg[j] = bit_sgn(wpk, j);
        float bb = b2[c];
        float s = bn2g[c] * rsqrtf(bn2v[c] + EPSV);
        float tt = bn2b[c] - bn2m[c] * s;
        #pragma unroll
        for (int p = 0; p < PTS; ++p) {
            unsigned a = sPkH[p][k];
            float acc = bb;
            #pragma unroll
            for (int j = 0; j < 16; ++j) {
                float sa = bit_sgn(a, j);
                acc += sa * wsg[j];
            }
            sXs[p][c][k] = clamp1(acc) * s + tt;
        }
    }
    // ---- D: t1 = sign(bn3(hardtanh(pd48 @ Wm^T + bm))) -> sPk1 (coalesced, exact r1 order) ----
    {
        int j = tid;
        float acc0 = 0.f, acc1 = 0.f, acc2 = 0.f, acc3 = 0.f;
        #pragma unroll
        for (int ib = 0; ib < 12; ++ib) {
            float4 w  = *(const float4*)&g_wmt[(ib * 256 + j) * 4];
            float4 q0 = *(const float4*)&sPd[0][ib * 4];
            float4 q1 = *(const float4*)&sPd[1][ib * 4];
            float4 q2 = *(const float4*)&sPd[2][ib * 4];
            float4 q3 = *(const float4*)&sPd[3][ib * 4];
            // i = ib*4+ii ascending, p inner — byte-identical to round-1 loop
            acc0 += w.x * q0.x; acc1 += w.x * q1.x; acc2 += w.x * q2.x; acc3 += w.x * q3.x;
            acc0 += w.y * q0.y; acc1 += w.y * q1.y; acc2 += w.y * q2.y; acc3 += w.y * q3.y;
            acc0 += w.z * q0.z; acc1 += w.z * q1.z; acc2 += w.z * q2.z; acc3 += w.z * q3.z;
            acc0 += w.w * q0.w; acc1 += w.w * q1.w; acc2 += w.w * q2.w; acc3 += w.w * q3.w;
        }
        float bb = bm[j];
        float s = bn3g[j] * rsqrtf(bn3v[j] + EPSV);
        float tt = bn3b[j] - bn3m[j] * s;
        float vv[PTS] = {acc0, acc1, acc2, acc3};
        #pragma unroll
        for (int p = 0; p < PTS; ++p) {
            float v = clamp1(vv[p] + bb) * s + tt;
            unsigned long long bp = __ballot(v > 0.f);
            unsigned long long bn_ = __ballot(v < 0.f);
            if ((lane & 15) == 0) {
                unsigned sh = lane & 48;
                sPk1[p][j >> 4] = ((unsigned)((bn_ >> sh) & 0xFFFFull) << 16) |
                                   (unsigned)((bp >> sh) & 0xFFFFull);
            }
        }
    }
    __syncthreads();

    // ---- E: t2 = sign(bn4(hardtanh(bigconv(t1, cw1)))) -> sPk2 (exact r1 chain) ----
    {
        int r = tid, g = r >> 4;
        unsigned wpk = g_cw1[r];
        float wsg[16];
        #pragma unroll
        for (int k = 0; k < 16; ++k) wsg[k] = bit_sgn(wpk, k);
        float bb = cb1[r];
        float s = bn4g[r] * rsqrtf(bn4v[r] + EPSV);
        float tt = bn4b[r] - bn4m[r] * s;
        #pragma unroll
        for (int p = 0; p < PTS; ++p) {
            unsigned a = sPk1[p][g];
            float acc = bb;
            #pragma unroll
            for (int k = 0; k < 16; ++k) {
                float sa = bit_sgn(a, k);
                acc += sa * wsg[k];
            }
            float v = clamp1(acc) * s + tt;
            unsigned long long bp = __ballot(v > 0.f);
            unsigned long long bn_ = __ballot(v < 0.f);
            if ((lane & 15) == 0) {
                unsigned sh = lane & 48;
                sPk2[p][r >> 4] = ((unsigned)((bn_ >> sh) & 0xFFFFull) << 16) |
                                   (unsigned)((bp >> sh) & 0xFFFFull);
            }
        }
    }
    __syncthreads();

    // ---- F: T = bn5(bigconv(t2, cw2)) (no hardtanh) -> sT (exact r1 chain) ----
    {
        int r = tid, g2 = r >> 4;
        unsigned wpk = g_cw2[r];
        float wsg[16];
        #pragma unroll
        for (int k = 0; k < 16; ++k) wsg[k] = bit_sgn(wpk, k);
        float bb = cb2[r];
        float s = bn5g[r] * rsqrtf(bn5v[r] + EPSV);
        float tt = bn5b[r] - bn5m[r] * s;
        int i = r >> 4, jj = r & 15;
        #pragma unroll
        for (int p = 0; p < PTS; ++p) {
            unsigned a = sPk2[p][g2];
            float acc = bb;
            #pragma unroll
            for (int k = 0; k < 16; ++k) {
                float sa = bit_sgn(a, k);
                acc += sa * wsg[k];
            }
            sT[p][i][jj] = acc * s + tt;
        }
    }
    __syncthreads();

    // ---- G: xt[c][i] = sum_j T[i][j]*xs[c][j] (exact r1 chain); pack signs -> sPkXt ----
    {
        int p = tid >> 6, ca = lane;
        int cb = ca + 64;
        int cbs = (cb < CT) ? cb : (CT - 1);
        float4 ra0 = *(const float4*)&sXs[p][ca][0];
        float4 ra1 = *(const float4*)&sXs[p][ca][4];
        float4 ra2 = *(const float4*)&sXs[p][ca][8];
        float4 ra3 = *(const float4*)&sXs[p][ca][12];
        float4 rb0 = *(const float4*)&sXs[p][cbs][0];
        float4 rb1 = *(const float4*)&sXs[p][cbs][4];
        float4 rb2 = *(const float4*)&sXs[p][cbs][8];
        float4 rb3 = *(const float4*)&sXs[p][cbs][12];
        unsigned pwa = 0, pwb = 0;
        #pragma unroll
        for (int i = 0; i < 16; ++i) {
            float4 t0 = *(const float4*)&sT[p][i][0];
            float4 t1 = *(const float4*)&sT[p][i][4];
            float4 t2 = *(const float4*)&sT[p][i][8];
            float4 t3 = *(const float4*)&sT[p][i][12];
            float acc = 0.f;
            acc += t0.x * ra0.x; acc += t0.y * ra0.y; acc += t0.z * ra0.z; acc += t0.w * ra0.w;
            acc += t1.x * ra1.x; acc += t1.y * ra1.y; acc += t1.z * ra1.z; acc += t1.w * ra1.w;
            acc += t2.x * ra2.x; acc += t2.y * ra2.y; acc += t2.z * ra2.z; acc += t2.w * ra2.w;
            acc += t3.x * ra3.x; acc += t3.y * ra3.y; acc += t3.z * ra3.z; acc += t3.w * ra3.w;
            pwa |= (acc > 0.f ? 1u : 0u) << i;
            pwa |= (acc < 0.f ? 1u : 0u) << (16 + i);
            float accb = 0.f;
            accb += t0.x * rb0.x; accb += t0.y * rb0.y; accb += t0.z * rb0.z; accb += t0.w * rb0.w;
            accb += t1.x * rb1.x; accb += t1.y * rb1.y; accb += t1.z * rb1.z; accb += t1.w * rb1.w;
            accb += t2.x * rb2.x; accb += t2.y * rb2.y; accb += t2.z * rb2.z; accb += t2.w * rb2.w;
            accb += t3.x * rb3.x; accb += t3.y * rb3.y; accb += t3.z * rb3.z; accb += t3.w * rb3.w;
            pwb |= (accb > 0.f ? 1u : 0u) << i;
            pwb |= (accb < 0.f ? 1u : 0u) << (16 + i);
        }
        sPkXt[p][ca] = pwa;
        if (cb < CT) sPkXt[p][cb] = pwb;
    }
    __syncthreads();

    // ---- H: y = bigconv(sign(xt), cw3) + cb3; sign(y) floats -> sS1 ----
    if (tid < CT * 2) {
        int q = tid, c = q >> 1;
        unsigned wp = g_cw3[0][q], wr = g_cw3[1][q];
        float bb = cb3[q];
        #pragma unroll
        for (int p = 0; p < PTS; ++p) {
            unsigned a = sPkXt[p][c];
            float v = (float)tdot(a, wp, wr) + bb;
            sS1[p][q] = sgnf(v);
        }
    }
    __syncthreads();

    // ---- pack sign(y) -> sPkY ----
    if (tid < PTS * 10) {
        int p = tid / 10, m = tid % 10;
        unsigned w = 0;
        #pragma unroll
        for (int k = 0; k < 16; ++k) {
            float v = sS1[p][m * 16 + k];
            w |= (v > 0.f ? 1u : 0u) << k;
            w |= (v < 0.f ? 1u : 0u) << (16 + k);
        }
        sPkY[p][m] = w;
    }
    __syncthreads();

    // ---- I: out = sign(y) . sign(Wf) + bf (packed; integer-exact) ----
    {
        int o = tid & 127, pp = tid >> 7;
        float bb = bf[o];
        unsigned a0[10], a1[10];
        #pragma unroll
        for (int m = 0; m < 10; ++m) { a0[m] = sPkY[2 * pp][m]; a1[m] = sPkY[2 * pp + 1][m]; }
        int acc0 = 0, acc1 = 0;
        #pragma unroll
        for (int m = 0; m < 10; ++m) {
            unsigned wp = g_wf[0][o * 10 + m], wr = g_wf[1][o * 10 + m];
            acc0 += __popc(a0[m] & wp) - __popc(a0[m] & wr);
            acc1 += __popc(a1[m] & wp) - __popc(a1[m] & wr);
        }
        out[(size_t)(nb + 2 * pp + 0) * COUT + o] = (float)acc0 + bb;
        out[(size_t)(nb + 2 * pp + 1) * COUT + o] = (float)acc1 + bb;
    }
}

extern "C" void kernel_launch(void* const* d_in, const int* in_sizes, int n_in,
                              void* d_out, int out_size, void* d_ws, size_t ws_size,
                              hipStream_t stream) {
    const float* x    = (const float*)d_in[0];
    const float* pos  = (const float*)d_in[1];
    const int*   col  = (const int*)d_in[2];
    const float* W1   = (const float*)d_in[3];
    const float* b1   = (const float*)d_in[4];
    const float* bn1g = (const float*)d_in[5];
    const float* bn1b = (const float*)d_in[6];
    const float* bn1m = (const float*)d_in[7];
    const float* bn1v = (const float*)d_in[8];
    const float* W2   = (const float*)d_in[9];
    const float* b2   = (const float*)d_in[10];
    const float* bn2g = (const float*)d_in[11];
    const float* bn2b = (const float*)d_in[12];
    const float* bn2m = (const float*)d_in[13];
    const float* bn2v = (const float*)d_in[14];
    const float* Wm   = (const float*)d_in[15];
    const float* bm   = (const float*)d_in[16];
    const float* bn3g = (const float*)d_in[17];
    const float* bn3b = (const float*)d_in[18];
    const float* bn3m = (const float*)d_in[19];
    const float* bn3v = (const float*)d_in[20];
    const float* cw1  = (const float*)d_in[21];
    const float* cb1  = (const float*)d_in[22];
    const float* bn4g = (const float*)d_in[23];
    const float* bn4b = (const float*)d_in[24];
    const float* bn4m = (const float*)d_in[25];
    const float* bn4v = (const float*)d_in[26];
    const float* cw2  = (const float*)d_in[27];
    const float* cb2  = (const float*)d_in[28];
    const float* bn5g = (const float*)d_in[29];
    const float* bn5b = (const float*)d_in[30];
    const float* bn5m = (const float*)d_in[31];
    const float* bn5v = (const float*)d_in[32];
    const float* cw3  = (const float*)d_in[33];
    const float* cb3  = (const float*)d_in[34];
    const float* Wf   = (const float*)d_in[35];
    const float* bf   = (const float*)d_in[36];
    float* outp = (float*)d_out;

    hipLaunchKernelGGL(prep_kernel, dim3(52), dim3(256), 0, stream, Wm, W2, cw1, cw2, cw3, Wf);
    hipLaunchKernelGGL(bixconv_kernel, dim3(NPTS / PTS), dim3(256), 0, stream,
        x, pos, col,
        W1, b1, bn1g, bn1b, bn1m, bn1v,
        b2, bn2g, bn2b, bn2m, bn2v,
        bm, bn3g, bn3b, bn3m, bn3v,
        cb1, bn4g, bn4b, bn4m, bn4v,
        cb2, bn5g, bn5b, bn5m, bn5v,
        cb3, bf, outp);
}

// Round 6
// 900.880 us; speedup vs baseline: 1.0219x; 1.0219x over previous
//
#include <hip/hip_runtime.h>

#define NPTS 100000
#define KN 16
#define DIM 3
#define CIN 64
#define CD 16
#define CT 80
#define COUT 128
#define PTS 4
#define EPSV 1e-5f

// ---- prepacked weights (written by prep_kernel every launch; deterministic) ----
__device__ __align__(16) float g_wmt[48 * 256];  // [(ib*256+j)*4+ii] = Wm[j*48+ib*4+ii]
__device__ unsigned g_w2[16];
__device__ unsigned g_cw1[256];
__device__ unsigned g_cw2[256];
__device__ unsigned g_cw3[2][160];
__device__ uint2    g_wf2[10 * 128];             // [m*128+o] = {w, rot16(w)}

__device__ __forceinline__ float clamp1(float x) { return fminf(1.f, fmaxf(-1.f, x)); }
__device__ __forceinline__ unsigned rot16(unsigned w) { return (w >> 16) | (w << 16); }

__device__ __forceinline__ unsigned packrow16(const float* __restrict__ w) {
    unsigned pos = 0, neg = 0;
    #pragma unroll
    for (int k = 0; k < 16; ++k) {
        pos |= (w[k] > 0.f ? 1u : 0u) << k;
        neg |= (w[k] < 0.f ? 1u : 0u) << k;
    }
    return (neg << 16) | pos;
}

// sign float {-1,0,1} from packed word bit k (exact ±1.0f / 0.0f)
__device__ __forceinline__ float bit_sgn(unsigned w, int k) {
    return (float)((int)((w >> k) & 1u) - (int)((w >> (k + 16)) & 1u));
}

// ternary dot (integer-exact) — ONLY safe where output feeds sign() of int+bias
__device__ __forceinline__ int tdot(unsigned a, unsigned wp, unsigned wr) {
    return __popc(a & wp) - __popc(a & wr);
}

__global__ void prep_kernel(const float* __restrict__ Wm, const float* __restrict__ W2,
                            const float* __restrict__ cw1, const float* __restrict__ cw2,
                            const float* __restrict__ cw3, const float* __restrict__ Wf) {
    int b = blockIdx.x, t = threadIdx.x;
    if (b < 48) {
        int ib = b >> 2, ii = b & 3;
        g_wmt[(ib * 256 + t) * 4 + ii] = Wm[t * 48 + b];
    } else if (b == 48) {
        g_cw1[t] = packrow16(cw1 + t * 16);
    } else if (b == 49) {
        g_cw2[t] = packrow16(cw2 + t * 16);
    } else if (b == 50) {
        if (t < 160) { unsigned w = packrow16(cw3 + t * 16); g_cw3[0][t] = w; g_cw3[1][t] = rot16(w); }
        else if (t < 176) { g_w2[t - 160] = packrow16(W2 + (t - 160) * 16); }
    } else {
        if (t < 128) {
            for (int m = 0; m < 10; ++m) {
                unsigned w = packrow16(Wf + t * 160 + m * 16);
                g_wf2[m * 128 + t] = make_uint2(w, rot16(w));
            }
        }
    }
}

__global__ __launch_bounds__(256, 4) void bixconv_kernel(
    const float* __restrict__ x, const float* __restrict__ pos, const int* __restrict__ col,
    const float* __restrict__ W1, const float* __restrict__ b1,
    const float* __restrict__ bn1g, const float* __restrict__ bn1b, const float* __restrict__ bn1m, const float* __restrict__ bn1v,
    const float* __restrict__ b2,
    const float* __restrict__ bn2g, const float* __restrict__ bn2b, const float* __restrict__ bn2m, const float* __restrict__ bn2v,
    const float* __restrict__ bm,
    const float* __restrict__ bn3g, const float* __restrict__ bn3b, const float* __restrict__ bn3m, const float* __restrict__ bn3v,
    const float* __restrict__ cb1,
    const float* __restrict__ bn4g, const float* __restrict__ bn4b, const float* __restrict__ bn4m, const float* __restrict__ bn4v,
    const float* __restrict__ cb2,
    const float* __restrict__ bn5g, const float* __restrict__ bn5b, const float* __restrict__ bn5m, const float* __restrict__ bn5v,
    const float* __restrict__ cb3, const float* __restrict__ bf,
    float* __restrict__ out)
{
    __shared__ int sIdx[PTS][KN];
    __shared__ __align__(16) float sPd[PTS][48];
    __shared__ __align__(16) float sXs[PTS][CT][20];   // rows 0..15: h2, rows 16..79: x[col]
    __shared__ __align__(16) float sT[PTS][KN][20];    // T (stage F output)
    __shared__ unsigned sPkH[PTS][16];                 // packed sign(h1)
    __shared__ unsigned sPk1[PTS][16];                 // packed sign(t1)
    __shared__ unsigned sPk2[PTS][16];                 // packed sign(t2)
    __shared__ unsigned sPkXt[PTS][CT];                // packed sign(xt)
    __shared__ unsigned sPkY[PTS][10];                 // packed sign(y)

    const int tid = threadIdx.x;
    const int lane = tid & 63;
    const int nb = blockIdx.x * PTS;

    // ---- A1: neighbor indices + relative positions ----
    if (tid < PTS * KN) {
        int p = tid >> 4, k = tid & 15;
        int n = nb + p;
        int idx = col[n * KN + k];
        sIdx[p][k] = idx;
        float ax = pos[n * 3 + 0], ay = pos[n * 3 + 1], az = pos[n * 3 + 2];
        sPd[p][k * 3 + 0] = pos[idx * 3 + 0] - ax;
        sPd[p][k * 3 + 1] = pos[idx * 3 + 1] - ay;
        sPd[p][k * 3 + 2] = pos[idx * 3 + 2] - az;
    }
    __syncthreads();

    // ---- A2: gather x[col] into xs rows 16..79 ----
    {
        int p = tid >> 6, c = lane;
        #pragma unroll
        for (int kb = 0; kb < 4; ++kb) {
            float4 v;
            v.x = x[(size_t)sIdx[p][kb * 4 + 0] * CIN + c];
            v.y = x[(size_t)sIdx[p][kb * 4 + 1] * CIN + c];
            v.z = x[(size_t)sIdx[p][kb * 4 + 2] * CIN + c];
            v.w = x[(size_t)sIdx[p][kb * 4 + 3] * CIN + c];
            *(float4*)&sXs[p][CD + c][kb * 4] = v;
        }
    }
    // ---- B: h1 = bn1(hardtanh(pd @ W1^T + b1)); ballot-pack signs -> sPkH ----
    {
        int c = tid & 15, k = tid >> 4;
        float w0 = W1[c * 3 + 0], w1 = W1[c * 3 + 1], w2v = W1[c * 3 + 2];
        float bb = b1[c];
        float s = bn1g[c] * rsqrtf(bn1v[c] + EPSV);
        float tt = bn1b[c] - bn1m[c] * s;
        #pragma unroll
        for (int p = 0; p < PTS; ++p) {
            float z = sPd[p][k * 3 + 0] * w0 + sPd[p][k * 3 + 1] * w1 + sPd[p][k * 3 + 2] * w2v + bb;
            float v = clamp1(z) * s + tt;
            unsigned long long bp = __ballot(v > 0.f);
            unsigned long long bn_ = __ballot(v < 0.f);
            if ((lane & 15) == 0) {
                unsigned sh = lane & 48;
                sPkH[p][k] = ((unsigned)((bn_ >> sh) & 0xFFFFull) << 16) |
                              (unsigned)((bp >> sh) & 0xFFFFull);
            }
        }
    }
    __syncthreads();

    // ---- C: h2 = bn2(hardtanh(...)) -> sXs rows 0..15 (EXACT r3/r4 sequential chain) ----
    {
        int c = tid & 15, k = tid >> 4;
        unsigned wpk = g_w2[c];
        float wsg[16];
        #pragma unroll
        for (int j = 0; j < 16; ++j) wsg[j] = bit_sgn(wpk, j);
        float bb = b2[c];
        float s = bn2g[c] * rsqrtf(bn2v[c] + EPSV);
        float tt = bn2b[c] - bn2m[c] * s;
        #pragma unroll
        for (int p = 0; p < PTS; ++p) {
            unsigned a = sPkH[p][k];
            float acc = bb;
            #pragma unroll
            for (int j = 0; j < 16; ++j) {
                float sa = bit_sgn(a, j);
                acc += sa * wsg[j];
            }
            sXs[p][c][k] = clamp1(acc) * s + tt;
        }
    }
    // ---- D: t1 = sign(bn3(hardtanh(pd48 @ Wm^T + bm))) -> sPk1 (exact r1 order) ----
    {
        int j = tid;
        float acc0 = 0.f, acc1 = 0.f, acc2 = 0.f, acc3 = 0.f;
        #pragma unroll
        for (int ib = 0; ib < 12; ++ib) {
            float4 w  = *(const float4*)&g_wmt[(ib * 256 + j) * 4];
            float4 q0 = *(const float4*)&sPd[0][ib * 4];
            float4 q1 = *(const float4*)&sPd[1][ib * 4];
            float4 q2 = *(const float4*)&sPd[2][ib * 4];
            float4 q3 = *(const float4*)&sPd[3][ib * 4];
            acc0 += w.x * q0.x; acc1 += w.x * q1.x; acc2 += w.x * q2.x; acc3 += w.x * q3.x;
            acc0 += w.y * q0.y; acc1 += w.y * q1.y; acc2 += w.y * q2.y; acc3 += w.y * q3.y;
            acc0 += w.z * q0.z; acc1 += w.z * q1.z; acc2 += w.z * q2.z; acc3 += w.z * q3.z;
            acc0 += w.w * q0.w; acc1 += w.w * q1.w; acc2 += w.w * q2.w; acc3 += w.w * q3.w;
        }
        float bb = bm[j];
        float s = bn3g[j] * rsqrtf(bn3v[j] + EPSV);
        float tt = bn3b[j] - bn3m[j] * s;
        float vv[PTS] = {acc0, acc1, acc2, acc3};
        #pragma unroll
        for (int p = 0; p < PTS; ++p) {
            float v = clamp1(vv[p] + bb) * s + tt;
            unsigned long long bp = __ballot(v > 0.f);
            unsigned long long bn_ = __ballot(v < 0.f);
            if ((lane & 15) == 0) {
                unsigned sh = lane & 48;
                sPk1[p][j >> 4] = ((unsigned)((bn_ >> sh) & 0xFFFFull) << 16) |
                                   (unsigned)((bp >> sh) & 0xFFFFull);
            }
        }
    }
    __syncthreads();

    // ---- E: t2 = sign(bn4(hardtanh(...))) -> sPk2 (EXACT r3/r4 sequential chain) ----
    {
        int r = tid, g = r >> 4;
        unsigned wpk = g_cw1[r];
        float wsg[16];
        #pragma unroll
        for (int k = 0; k < 16; ++k) wsg[k] = bit_sgn(wpk, k);
        float bb = cb1[r];
        float s = bn4g[r] * rsqrtf(bn4v[r] + EPSV);
        float tt = bn4b[r] - bn4m[r] * s;
        #pragma unroll
        for (int p = 0; p < PTS; ++p) {
            unsigned a = sPk1[p][g];
            float acc = bb;
            #pragma unroll
            for (int k = 0; k < 16; ++k) {
                float sa = bit_sgn(a, k);
                acc += sa * wsg[k];
            }
            float v = clamp1(acc) * s + tt;
            unsigned long long bp = __ballot(v > 0.f);
            unsigned long long bn_ = __ballot(v < 0.f);
            if ((lane & 15) == 0) {
                unsigned sh = lane & 48;
                sPk2[p][r >> 4] = ((unsigned)((bn_ >> sh) & 0xFFFFull) << 16) |
                                   (unsigned)((bp >> sh) & 0xFFFFull);
            }
        }
    }
    __syncthreads();

    // ---- F: T = bn5(...) (no hardtanh) -> sT (EXACT r3/r4 sequential chain) ----
    {
        int r = tid, g2 = r >> 4;
        unsigned wpk = g_cw2[r];
        float wsg[16];
        #pragma unroll
        for (int k = 0; k < 16; ++k) wsg[k] = bit_sgn(wpk, k);
        float bb = cb2[r];
        float s = bn5g[r] * rsqrtf(bn5v[r] + EPSV);
        float tt = bn5b[r] - bn5m[r] * s;
        int i = r >> 4, jj = r & 15;
        #pragma unroll
        for (int p = 0; p < PTS; ++p) {
            unsigned a = sPk2[p][g2];
            float acc = bb;
            #pragma unroll
            for (int k = 0; k < 16; ++k) {
                float sa = bit_sgn(a, k);
                acc += sa * wsg[k];
            }
            sT[p][i][jj] = acc * s + tt;
        }
    }
    __syncthreads();

    // ---- G: xt[c][i] = sum_j T[i][j]*xs[c][j]; wave=p, lane=(cg,i); ballot-pack -> sPkXt ----
    {
        int p = tid >> 6;
        int i = lane & 15, cg = lane >> 4;
        float4 t0 = *(const float4*)&sT[p][i][0];
        float4 t1 = *(const float4*)&sT[p][i][4];
        float4 t2 = *(const float4*)&sT[p][i][8];
        float4 t3 = *(const float4*)&sT[p][i][12];
        #pragma unroll
        for (int it = 0; it < 20; ++it) {
            int c = 4 * it + cg;
            float4 r0 = *(const float4*)&sXs[p][c][0];
            float4 r1 = *(const float4*)&sXs[p][c][4];
            float4 r2 = *(const float4*)&sXs[p][c][8];
            float4 r3 = *(const float4*)&sXs[p][c][12];
            float acc = 0.f;
            acc += t0.x * r0.x; acc += t0.y * r0.y; acc += t0.z * r0.z; acc += t0.w * r0.w;
            acc += t1.x * r1.x; acc += t1.y * r1.y; acc += t1.z * r1.z; acc += t1.w * r1.w;
            acc += t2.x * r2.x; acc += t2.y * r2.y; acc += t2.z * r2.z; acc += t2.w * r2.w;
            acc += t3.x * r3.x; acc += t3.y * r3.y; acc += t3.z * r3.z; acc += t3.w * r3.w;
            unsigned long long bp = __ballot(acc > 0.f);
            unsigned long long bn_ = __ballot(acc < 0.f);
            if ((lane & 15) == 0) {
                unsigned sh = lane & 48;
                sPkXt[p][c] = ((unsigned)((bn_ >> sh) & 0xFFFFull) << 16) |
                               (unsigned)((bp >> sh) & 0xFFFFull);
            }
        }
    }
    __syncthreads();

    // ---- H: y = bigconv(sign(xt), cw3) + cb3; ballot-pack sign(y) -> sPkY (tdot-safe) ----
    if (tid < CT * 2) {
        int q = tid, c = q >> 1;
        unsigned wp = g_cw3[0][q], wr = g_cw3[1][q];
        float bb = cb3[q];
        #pragma unroll
        for (int p = 0; p < PTS; ++p) {
            unsigned a = sPkXt[p][c];
            float v = (float)tdot(a, wp, wr) + bb;
            unsigned long long bp = __ballot(v > 0.f);
            unsigned long long bn_ = __ballot(v < 0.f);
            if ((lane & 15) == 0) {
                unsigned sh = lane & 48;
                sPkY[p][q >> 4] = ((unsigned)((bn_ >> sh) & 0xFFFFull) << 16) |
                                   (unsigned)((bp >> sh) & 0xFFFFull);
            }
        }
    }
    __syncthreads();

    // ---- I: out = sign(y) . sign(Wf) + bf (packed; integer-exact; coalesced uint2) ----
    {
        int o = tid & 127, pp = tid >> 7;
        float bb = bf[o];
        unsigned a0[10], a1[10];
        #pragma unroll
        for (int m = 0; m < 10; ++m) { a0[m] = sPkY[2 * pp][m]; a1[m] = sPkY[2 * pp + 1][m]; }
        int acc0 = 0, acc1 = 0;
        #pragma unroll
        for (int m = 0; m < 10; ++m) {
            uint2 w = g_wf2[m * 128 + o];
            acc0 += __popc(a0[m] & w.x) - __popc(a0[m] & w.y);
            acc1 += __popc(a1[m] & w.x) - __popc(a1[m] & w.y);
        }
        out[(size_t)(nb + 2 * pp + 0) * COUT + o] = (float)acc0 + bb;
        out[(size_t)(nb + 2 * pp + 1) * COUT + o] = (float)acc1 + bb;
    }
}

extern "C" void kernel_launch(void* const* d_in, const int* in_sizes, int n_in,
                              void* d_out, int out_size, void* d_ws, size_t ws_size,
                              hipStream_t stream) {
    const float* x    = (const float*)d_in[0];
    const float* pos  = (const float*)d_in[1];
    const int*   col  = (const int*)d_in[2];
    const float* W1   = (const float*)d_in[3];
    const float* b1   = (const float*)d_in[4];
    const float* bn1g = (const float*)d_in[5];
    const float* bn1b = (const float*)d_in[6];
    const float* bn1m = (const float*)d_in[7];
    const float* bn1v = (const float*)d_in[8];
    const float* W2   = (const float*)d_in[9];
    const float* b2   = (const float*)d_in[10];
    const float* bn2g = (const float*)d_in[11];
    const float* bn2b = (const float*)d_in[12];
    const float* bn2m = (const float*)d_in[13];
    const float* bn2v = (const float*)d_in[14];
    const float* Wm   = (const float*)d_in[15];
    const float* bm   = (const float*)d_in[16];
    const float* bn3g = (const float*)d_in[17];
    const float* bn3b = (const float*)d_in[18];
    const float* bn3m = (const float*)d_in[19];
    const float* bn3v = (const float*)d_in[20];
    const float* cw1  = (const float*)d_in[21];
    const float* cb1  = (const float*)d_in[22];
    const float* bn4g = (const float*)d_in[23];
    const float* bn4b = (const float*)d_in[24];
    const float* bn4m = (const float*)d_in[25];
    const float* bn4v = (const float*)d_in[26];
    const float* cw2  = (const float*)d_in[27];
    const float* cb2  = (const float*)d_in[28];
    const float* bn5g = (const float*)d_in[29];
    const float* bn5b = (const float*)d_in[30];
    const float* bn5m = (const float*)d_in[31];
    const float* bn5v = (const float*)d_in[32];
    const float* cw3  = (const float*)d_in[33];
    const float* cb3  = (const float*)d_in[34];
    const float* Wf   = (const float*)d_in[35];
    const float* bf   = (const float*)d_in[36];
    float* outp = (float*)d_out;

    hipLaunchKernelGGL(prep_kernel, dim3(52), dim3(256), 0, stream, Wm, W2, cw1, cw2, cw3, Wf);
    hipLaunchKernelGGL(bixconv_kernel, dim3(NPTS / PTS), dim3(256), 0, stream,
        x, pos, col,
        W1, b1, bn1g, bn1b, bn1m, bn1v,
        b2, bn2g, bn2b, bn2m, bn2v,
        bm, bn3g, bn3b, bn3m, bn3v,
        cb1, bn4g, bn4b, bn4m, bn4v,
        cb2, bn5g, bn5b, bn5m, bn5v,
        cb3, bf, outp);
}

// Round 7
// 391.770 us; speedup vs baseline: 2.3500x; 2.2995x over previous
//
#include <hip/hip_runtime.h>

#define NPTS 100000
#define KN 16
#define DIM 3
#define CIN 64
#define CD 16
#define CT 80
#define COUT 128
#define PTS 4
#define EPSV 1e-5f

// ---- prepacked weights (written by prep_kernel every launch; deterministic) ----
__device__ __align__(16) float g_wmt[48 * 256];  // [(ib*256+j)*4+ii] = Wm[j*48+ib*4+ii]
__device__ unsigned g_w2[16];
__device__ unsigned g_cw1[256];
__device__ unsigned g_cw2[256];
__device__ unsigned g_cw3[2][160];
__device__ uint2    g_wf2[10 * 128];             // [m*128+o] = {w, rot16(w)}

__device__ __forceinline__ float clamp1(float x) { return fminf(1.f, fmaxf(-1.f, x)); }
__device__ __forceinline__ unsigned rot16(unsigned w) { return (w >> 16) | (w << 16); }

__device__ __forceinline__ unsigned packrow16(const float* __restrict__ w) {
    unsigned pos = 0, neg = 0;
    #pragma unroll
    for (int k = 0; k < 16; ++k) {
        pos |= (w[k] > 0.f ? 1u : 0u) << k;
        neg |= (w[k] < 0.f ? 1u : 0u) << k;
    }
    return (neg << 16) | pos;
}

// sign float {-1,0,1} from packed word bit k (exact ±1.0f / 0.0f)
__device__ __forceinline__ float bit_sgn(unsigned w, int k) {
    return (float)((int)((w >> k) & 1u) - (int)((w >> (k + 16)) & 1u));
}

// ternary dot (integer-exact) — ONLY safe where output feeds sign() of int+bias
__device__ __forceinline__ int tdot(unsigned a, unsigned wp, unsigned wr) {
    return __popc(a & wp) - __popc(a & wr);
}

__global__ void prep_kernel(const float* __restrict__ Wm, const float* __restrict__ W2,
                            const float* __restrict__ cw1, const float* __restrict__ cw2,
                            const float* __restrict__ cw3, const float* __restrict__ Wf) {
    int b = blockIdx.x, t = threadIdx.x;
    if (b < 48) {
        int ib = b >> 2, ii = b & 3;
        g_wmt[(ib * 256 + t) * 4 + ii] = Wm[t * 48 + b];
    } else if (b == 48) {
        g_cw1[t] = packrow16(cw1 + t * 16);
    } else if (b == 49) {
        g_cw2[t] = packrow16(cw2 + t * 16);
    } else if (b == 50) {
        if (t < 160) { unsigned w = packrow16(cw3 + t * 16); g_cw3[0][t] = w; g_cw3[1][t] = rot16(w); }
        else if (t < 176) { g_w2[t - 160] = packrow16(W2 + (t - 160) * 16); }
    } else {
        if (t < 128) {
            for (int m = 0; m < 10; ++m) {
                unsigned w = packrow16(Wf + t * 160 + m * 16);
                g_wf2[m * 128 + t] = make_uint2(w, rot16(w));
            }
        }
    }
}

__global__ __launch_bounds__(256) void bixconv_kernel(
    const float* __restrict__ x, const float* __restrict__ pos, const int* __restrict__ col,
    const float* __restrict__ W1, const float* __restrict__ b1,
    const float* __restrict__ bn1g, const float* __restrict__ bn1b, const float* __restrict__ bn1m, const float* __restrict__ bn1v,
    const float* __restrict__ b2,
    const float* __restrict__ bn2g, const float* __restrict__ bn2b, const float* __restrict__ bn2m, const float* __restrict__ bn2v,
    const float* __restrict__ bm,
    const float* __restrict__ bn3g, const float* __restrict__ bn3b, const float* __restrict__ bn3m, const float* __restrict__ bn3v,
    const float* __restrict__ cb1,
    const float* __restrict__ bn4g, const float* __restrict__ bn4b, const float* __restrict__ bn4m, const float* __restrict__ bn4v,
    const float* __restrict__ cb2,
    const float* __restrict__ bn5g, const float* __restrict__ bn5b, const float* __restrict__ bn5m, const float* __restrict__ bn5v,
    const float* __restrict__ cb3, const float* __restrict__ bf,
    float* __restrict__ out)
{
    __shared__ int sIdx[PTS][KN];
    __shared__ __align__(16) float sPd[PTS][48];
    __shared__ __align__(16) float sXs[PTS][CT][20];   // rows 0..15: h2, rows 16..79: x[col]
    __shared__ __align__(16) float sT[PTS][KN][20];    // T (stage F output)
    __shared__ unsigned sPkH[PTS][16];                 // packed sign(h1)
    __shared__ unsigned sPk1[PTS][16];                 // packed sign(t1)
    __shared__ unsigned sPk2[PTS][16];                 // packed sign(t2)
    __shared__ unsigned sPkXt[PTS][CT];                // packed sign(xt)
    __shared__ unsigned sPkY[PTS][10];                 // packed sign(y)

    const int tid = threadIdx.x;
    const int lane = tid & 63;
    const int nb = blockIdx.x * PTS;

    // ---- A1: neighbor indices + relative positions ----
    if (tid < PTS * KN) {
        int p = tid >> 4, k = tid & 15;
        int n = nb + p;
        int idx = col[n * KN + k];
        sIdx[p][k] = idx;
        float ax = pos[n * 3 + 0], ay = pos[n * 3 + 1], az = pos[n * 3 + 2];
        sPd[p][k * 3 + 0] = pos[idx * 3 + 0] - ax;
        sPd[p][k * 3 + 1] = pos[idx * 3 + 1] - ay;
        sPd[p][k * 3 + 2] = pos[idx * 3 + 2] - az;
    }
    __syncthreads();

    // ---- A2: gather x[col] into xs rows 16..79 ----
    {
        int p = tid >> 6, c = lane;
        #pragma unroll
        for (int kb = 0; kb < 4; ++kb) {
            float4 v;
            v.x = x[(size_t)sIdx[p][kb * 4 + 0] * CIN + c];
            v.y = x[(size_t)sIdx[p][kb * 4 + 1] * CIN + c];
            v.z = x[(size_t)sIdx[p][kb * 4 + 2] * CIN + c];
            v.w = x[(size_t)sIdx[p][kb * 4 + 3] * CIN + c];
            *(float4*)&sXs[p][CD + c][kb * 4] = v;
        }
    }
    // ---- B: h1 = bn1(hardtanh(pd @ W1^T + b1)); ballot-pack signs -> sPkH ----
    {
        int c = tid & 15, k = tid >> 4;
        float w0 = W1[c * 3 + 0], w1 = W1[c * 3 + 1], w2v = W1[c * 3 + 2];
        float bb = b1[c];
        float s = bn1g[c] * rsqrtf(bn1v[c] + EPSV);
        float tt = bn1b[c] - bn1m[c] * s;
        #pragma unroll
        for (int p = 0; p < PTS; ++p) {
            float z = sPd[p][k * 3 + 0] * w0 + sPd[p][k * 3 + 1] * w1 + sPd[p][k * 3 + 2] * w2v + bb;
            float v = clamp1(z) * s + tt;
            unsigned long long bp = __ballot(v > 0.f);
            unsigned long long bn_ = __ballot(v < 0.f);
            if ((lane & 15) == 0) {
                unsigned sh = lane & 48;
                sPkH[p][k] = ((unsigned)((bn_ >> sh) & 0xFFFFull) << 16) |
                              (unsigned)((bp >> sh) & 0xFFFFull);
            }
        }
    }
    __syncthreads();

    // ---- C: h2 = bn2(hardtanh(...)) -> sXs rows 0..15 (EXACT r3/r4 sequential chain) ----
    {
        int c = tid & 15, k = tid >> 4;
        unsigned wpk = g_w2[c];
        float wsg[16];
        #pragma unroll
        for (int j = 0; j < 16; ++j) wsg[j] = bit_sgn(wpk, j);
        float bb = b2[c];
        float s = bn2g[c] * rsqrtf(bn2v[c] + EPSV);
        float tt = bn2b[c] - bn2m[c] * s;
        #pragma unroll
        for (int p = 0; p < PTS; ++p) {
            unsigned a = sPkH[p][k];
            float acc = bb;
            #pragma unroll
            for (int j = 0; j < 16; ++j) {
                float sa = bit_sgn(a, j);
                acc += sa * wsg[j];
            }
            sXs[p][c][k] = clamp1(acc) * s + tt;
        }
    }
    // ---- D: t1 = sign(bn3(hardtanh(pd48 @ Wm^T + bm))) -> sPk1 (exact order; unroll-limited) ----
    {
        int j = tid;
        float acc0 = 0.f, acc1 = 0.f, acc2 = 0.f, acc3 = 0.f;
        #pragma unroll 2
        for (int ib = 0; ib < 12; ++ib) {
            float4 w  = *(const float4*)&g_wmt[(ib * 256 + j) * 4];
            float4 q0 = *(const float4*)&sPd[0][ib * 4];
            float4 q1 = *(const float4*)&sPd[1][ib * 4];
            float4 q2 = *(const float4*)&sPd[2][ib * 4];
            float4 q3 = *(const float4*)&sPd[3][ib * 4];
            acc0 += w.x * q0.x; acc1 += w.x * q1.x; acc2 += w.x * q2.x; acc3 += w.x * q3.x;
            acc0 += w.y * q0.y; acc1 += w.y * q1.y; acc2 += w.y * q2.y; acc3 += w.y * q3.y;
            acc0 += w.z * q0.z; acc1 += w.z * q1.z; acc2 += w.z * q2.z; acc3 += w.z * q3.z;
            acc0 += w.w * q0.w; acc1 += w.w * q1.w; acc2 += w.w * q2.w; acc3 += w.w * q3.w;
        }
        float bb = bm[j];
        float s = bn3g[j] * rsqrtf(bn3v[j] + EPSV);
        float tt = bn3b[j] - bn3m[j] * s;
        float vv[PTS] = {acc0, acc1, acc2, acc3};
        #pragma unroll
        for (int p = 0; p < PTS; ++p) {
            float v = clamp1(vv[p] + bb) * s + tt;
            unsigned long long bp = __ballot(v > 0.f);
            unsigned long long bn_ = __ballot(v < 0.f);
            if ((lane & 15) == 0) {
                unsigned sh = lane & 48;
                sPk1[p][j >> 4] = ((unsigned)((bn_ >> sh) & 0xFFFFull) << 16) |
                                   (unsigned)((bp >> sh) & 0xFFFFull);
            }
        }
    }
    __syncthreads();

    // ---- E: t2 = sign(bn4(hardtanh(...))) -> sPk2 (EXACT r3/r4 sequential chain) ----
    {
        int r = tid, g = r >> 4;
        unsigned wpk = g_cw1[r];
        float wsg[16];
        #pragma unroll
        for (int k = 0; k < 16; ++k) wsg[k] = bit_sgn(wpk, k);
        float bb = cb1[r];
        float s = bn4g[r] * rsqrtf(bn4v[r] + EPSV);
        float tt = bn4b[r] - bn4m[r] * s;
        #pragma unroll
        for (int p = 0; p < PTS; ++p) {
            unsigned a = sPk1[p][g];
            float acc = bb;
            #pragma unroll
            for (int k = 0; k < 16; ++k) {
                float sa = bit_sgn(a, k);
                acc += sa * wsg[k];
            }
            float v = clamp1(acc) * s + tt;
            unsigned long long bp = __ballot(v > 0.f);
            unsigned long long bn_ = __ballot(v < 0.f);
            if ((lane & 15) == 0) {
                unsigned sh = lane & 48;
                sPk2[p][r >> 4] = ((unsigned)((bn_ >> sh) & 0xFFFFull) << 16) |
                                   (unsigned)((bp >> sh) & 0xFFFFull);
            }
        }
    }
    __syncthreads();

    // ---- F: T = bn5(...) (no hardtanh) -> sT (EXACT r3/r4 sequential chain) ----
    {
        int r = tid, g2 = r >> 4;
        unsigned wpk = g_cw2[r];
        float wsg[16];
        #pragma unroll
        for (int k = 0; k < 16; ++k) wsg[k] = bit_sgn(wpk, k);
        float bb = cb2[r];
        float s = bn5g[r] * rsqrtf(bn5v[r] + EPSV);
        float tt = bn5b[r] - bn5m[r] * s;
        int i = r >> 4, jj = r & 15;
        #pragma unroll
        for (int p = 0; p < PTS; ++p) {
            unsigned a = sPk2[p][g2];
            float acc = bb;
            #pragma unroll
            for (int k = 0; k < 16; ++k) {
                float sa = bit_sgn(a, k);
                acc += sa * wsg[k];
            }
            sT[p][i][jj] = acc * s + tt;
        }
    }
    __syncthreads();

    // ---- G: xt[c][i] = sum_j T[i][j]*xs[c][j]; wave=p, lane=(cg,i); unroll-limited ----
    {
        int p = tid >> 6;
        int i = lane & 15, cg = lane >> 4;
        float4 t0 = *(const float4*)&sT[p][i][0];
        float4 t1 = *(const float4*)&sT[p][i][4];
        float4 t2 = *(const float4*)&sT[p][i][8];
        float4 t3 = *(const float4*)&sT[p][i][12];
        #pragma unroll 2
        for (int it = 0; it < 20; ++it) {
            int c = 4 * it + cg;
            float4 r0 = *(const float4*)&sXs[p][c][0];
            float4 r1 = *(const float4*)&sXs[p][c][4];
            float4 r2 = *(const float4*)&sXs[p][c][8];
            float4 r3 = *(const float4*)&sXs[p][c][12];
            float acc = 0.f;
            acc += t0.x * r0.x; acc += t0.y * r0.y; acc += t0.z * r0.z; acc += t0.w * r0.w;
            acc += t1.x * r1.x; acc += t1.y * r1.y; acc += t1.z * r1.z; acc += t1.w * r1.w;
            acc += t2.x * r2.x; acc += t2.y * r2.y; acc += t2.z * r2.z; acc += t2.w * r2.w;
            acc += t3.x * r3.x; acc += t3.y * r3.y; acc += t3.z * r3.z; acc += t3.w * r3.w;
            unsigned long long bp = __ballot(acc > 0.f);
            unsigned long long bn_ = __ballot(acc < 0.f);
            if ((lane & 15) == 0) {
                unsigned sh = lane & 48;
                sPkXt[p][c] = ((unsigned)((bn_ >> sh) & 0xFFFFull) << 16) |
                               (unsigned)((bp >> sh) & 0xFFFFull);
            }
        }
    }
    __syncthreads();

    // ---- H: y = bigconv(sign(xt), cw3) + cb3; ballot-pack sign(y) -> sPkY (tdot-safe) ----
    if (tid < CT * 2) {
        int q = tid, c = q >> 1;
        unsigned wp = g_cw3[0][q], wr = g_cw3[1][q];
        float bb = cb3[q];
        #pragma unroll
        for (int p = 0; p < PTS; ++p) {
            unsigned a = sPkXt[p][c];
            float v = (float)tdot(a, wp, wr) + bb;
            unsigned long long bp = __ballot(v > 0.f);
            unsigned long long bn_ = __ballot(v < 0.f);
            if ((lane & 15) == 0) {
                unsigned sh = lane & 48;
                sPkY[p][q >> 4] = ((unsigned)((bn_ >> sh) & 0xFFFFull) << 16) |
                                   (unsigned)((bp >> sh) & 0xFFFFull);
            }
        }
    }
    __syncthreads();

    // ---- I: out = sign(y) . sign(Wf) + bf (packed; integer-exact; coalesced uint2) ----
    {
        int o = tid & 127, pp = tid >> 7;
        float bb = bf[o];
        unsigned a0[10], a1[10];
        #pragma unroll
        for (int m = 0; m < 10; ++m) { a0[m] = sPkY[2 * pp][m]; a1[m] = sPkY[2 * pp + 1][m]; }
        int acc0 = 0, acc1 = 0;
        #pragma unroll
        for (int m = 0; m < 10; ++m) {
            uint2 w = g_wf2[m * 128 + o];
            acc0 += __popc(a0[m] & w.x) - __popc(a0[m] & w.y);
            acc1 += __popc(a1[m] & w.x) - __popc(a1[m] & w.y);
        }
        out[(size_t)(nb + 2 * pp + 0) * COUT + o] = (float)acc0 + bb;
        out[(size_t)(nb + 2 * pp + 1) * COUT + o] = (float)acc1 + bb;
    }
}

extern "C" void kernel_launch(void* const* d_in, const int* in_sizes, int n_in,
                              void* d_out, int out_size, void* d_ws, size_t ws_size,
                              hipStream_t stream) {
    const float* x    = (const float*)d_in[0];
    const float* pos  = (const float*)d_in[1];
    const int*   col  = (const int*)d_in[2];
    const float* W1   = (const float*)d_in[3];
    const float* b1   = (const float*)d_in[4];
    const float* bn1g = (const float*)d_in[5];
    const float* bn1b = (const float*)d_in[6];
    const float* bn1m = (const float*)d_in[7];
    const float* bn1v = (const float*)d_in[8];
    const float* W2   = (const float*)d_in[9];
    const float* b2   = (const float*)d_in[10];
    const float* bn2g = (const float*)d_in[11];
    const float* bn2b = (const float*)d_in[12];
    const float* bn2m = (const float*)d_in[13];
    const float* bn2v = (const float*)d_in[14];
    const float* Wm   = (const float*)d_in[15];
    const float* bm   = (const float*)d_in[16];
    const float* bn3g = (const float*)d_in[17];
    const float* bn3b = (const float*)d_in[18];
    const float* bn3m = (const float*)d_in[19];
    const float* bn3v = (const float*)d_in[20];
    const float* cw1  = (const float*)d_in[21];
    const float* cb1  = (const float*)d_in[22];
    const float* bn4g = (const float*)d_in[23];
    const float* bn4b = (const float*)d_in[24];
    const float* bn4m = (const float*)d_in[25];
    const float* bn4v = (const float*)d_in[26];
    const float* cw2  = (const float*)d_in[27];
    const float* cb2  = (const float*)d_in[28];
    const float* bn5g = (const float*)d_in[29];
    const float* bn5b = (const float*)d_in[30];
    const float* bn5m = (const float*)d_in[31];
    const float* bn5v = (const float*)d_in[32];
    const float* cw3  = (const float*)d_in[33];
    const float* cb3  = (const float*)d_in[34];
    const float* Wf   = (const float*)d_in[35];
    const float* bf   = (const float*)d_in[36];
    float* outp = (float*)d_out;

    hipLaunchKernelGGL(prep_kernel, dim3(52), dim3(256), 0, stream, Wm, W2, cw1, cw2, cw3, Wf);
    hipLaunchKernelGGL(bixconv_kernel, dim3(NPTS / PTS), dim3(256), 0, stream,
        x, pos, col,
        W1, b1, bn1g, bn1b, bn1m, bn1v,
        b2, bn2g, bn2b, bn2m, bn2v,
        bm, bn3g, bn3b, bn3m, bn3v,
        cb1, bn4g, bn4b, bn4m, bn4v,
        cb2, bn5g, bn5b, bn5m, bn5v,
        cb3, bf, outp);
}

// Round 8
// 328.737 us; speedup vs baseline: 2.8006x; 1.1917x over previous
//
#include <hip/hip_runtime.h>

#define NPTS 100000
#define KN 16
#define DIM 3
#define CIN 64
#define CD 16
#define CT 80
#define COUT 128
#define PTS 4
#define EPSV 1e-5f

// ---- prepacked weights (written by prep_kernel every launch; deterministic) ----
__device__ __align__(16) float g_wmt[48 * 256];  // [(ib*256+j)*4+ii] = Wm[j*48+ib*4+ii]
__device__ __align__(16) float g_w2f[256];       // sign(W2) floats, [c*16+j]
__device__ __align__(16) float g_cw1f[4096];     // sign(cw1) floats, [r*16+k]
__device__ __align__(16) float g_cw2f[4096];     // sign(cw2) floats, [r*16+k]
__device__ unsigned g_cw3[2][160];
__device__ uint2    g_wf2[10 * 128];             // [m*128+o] = {w, rot16(w)}

__device__ __forceinline__ float sgnf(float x) {
    return (x > 0.f) ? 1.f : ((x < 0.f) ? -1.f : 0.f);
}
__device__ __forceinline__ float clamp1(float x) { return fminf(1.f, fmaxf(-1.f, x)); }
__device__ __forceinline__ unsigned rot16(unsigned w) { return (w >> 16) | (w << 16); }

__device__ __forceinline__ unsigned packrow16(const float* __restrict__ w) {
    unsigned pos = 0, neg = 0;
    #pragma unroll
    for (int k = 0; k < 16; ++k) {
        pos |= (w[k] > 0.f ? 1u : 0u) << k;
        neg |= (w[k] < 0.f ? 1u : 0u) << k;
    }
    return (neg << 16) | pos;
}

// ternary dot (integer-exact) — ONLY safe where output feeds sign() of int+bias
__device__ __forceinline__ int tdot(unsigned a, unsigned wp, unsigned wr) {
    return __popc(a & wp) - __popc(a & wr);
}

__global__ void prep_kernel(const float* __restrict__ Wm, const float* __restrict__ W2,
                            const float* __restrict__ cw1, const float* __restrict__ cw2,
                            const float* __restrict__ cw3, const float* __restrict__ Wf) {
    int b = blockIdx.x, t = threadIdx.x;
    if (b < 48) {
        int ib = b >> 2, ii = b & 3;
        g_wmt[(ib * 256 + t) * 4 + ii] = Wm[t * 48 + b];
    } else if (b == 48) {
        #pragma unroll
        for (int k = 0; k < 16; ++k) g_cw1f[t * 16 + k] = sgnf(cw1[t * 16 + k]);
    } else if (b == 49) {
        #pragma unroll
        for (int k = 0; k < 16; ++k) g_cw2f[t * 16 + k] = sgnf(cw2[t * 16 + k]);
    } else if (b == 50) {
        if (t < 160) { unsigned w = packrow16(cw3 + t * 16); g_cw3[0][t] = w; g_cw3[1][t] = rot16(w); }
        else if (t < 176) {
            int c = t - 160;
            #pragma unroll
            for (int j = 0; j < 16; ++j) g_w2f[c * 16 + j] = sgnf(W2[c * 16 + j]);
        }
    } else {
        if (t < 128) {
            for (int m = 0; m < 10; ++m) {
                unsigned w = packrow16(Wf + t * 160 + m * 16);
                g_wf2[m * 128 + t] = make_uint2(w, rot16(w));
            }
        }
    }
}

__global__ __launch_bounds__(256) void bixconv_kernel(
    const float* __restrict__ x, const float* __restrict__ pos, const int* __restrict__ col,
    const float* __restrict__ W1, const float* __restrict__ b1,
    const float* __restrict__ bn1g, const float* __restrict__ bn1b, const float* __restrict__ bn1m, const float* __restrict__ bn1v,
    const float* __restrict__ b2,
    const float* __restrict__ bn2g, const float* __restrict__ bn2b, const float* __restrict__ bn2m, const float* __restrict__ bn2v,
    const float* __restrict__ bm,
    const float* __restrict__ bn3g, const float* __restrict__ bn3b, const float* __restrict__ bn3m, const float* __restrict__ bn3v,
    const float* __restrict__ cb1,
    const float* __restrict__ bn4g, const float* __restrict__ bn4b, const float* __restrict__ bn4m, const float* __restrict__ bn4v,
    const float* __restrict__ cb2,
    const float* __restrict__ bn5g, const float* __restrict__ bn5b, const float* __restrict__ bn5m, const float* __restrict__ bn5v,
    const float* __restrict__ cb3, const float* __restrict__ bf,
    float* __restrict__ out)
{
    __shared__ int sIdx[PTS][KN];
    __shared__ __align__(16) float sPd[PTS][48];
    __shared__ __align__(16) float sXs[PTS][CT][20];   // rows 0..15: h2, rows 16..79: x[col]
    __shared__ __align__(16) float sT[PTS][KN][20];    // T (stage F output)
    __shared__ __align__(16) float sSgnH[PTS][KN][16]; // sign(h1) floats, [p][k][c]
    __shared__ __align__(16) float sSgn1[PTS][256];    // sign(t1) floats, [p][j]
    __shared__ __align__(16) float sSgn2[PTS][256];    // sign(t2) floats, [p][r]
    __shared__ unsigned sPkXt[PTS][CT];                // packed sign(xt)
    __shared__ unsigned sPkY[PTS][10];                 // packed sign(y)

    const int tid = threadIdx.x;
    const int lane = tid & 63;
    const int nb = blockIdx.x * PTS;

    // ---- A1: neighbor indices + relative positions ----
    if (tid < PTS * KN) {
        int p = tid >> 4, k = tid & 15;
        int n = nb + p;
        int idx = col[n * KN + k];
        sIdx[p][k] = idx;
        float ax = pos[n * 3 + 0], ay = pos[n * 3 + 1], az = pos[n * 3 + 2];
        sPd[p][k * 3 + 0] = pos[idx * 3 + 0] - ax;
        sPd[p][k * 3 + 1] = pos[idx * 3 + 1] - ay;
        sPd[p][k * 3 + 2] = pos[idx * 3 + 2] - az;
    }
    __syncthreads();

    // ---- A2: gather x[col] into xs rows 16..79 ----
    {
        int p = tid >> 6, c = lane;
        #pragma unroll
        for (int kb = 0; kb < 4; ++kb) {
            float4 v;
            v.x = x[(size_t)sIdx[p][kb * 4 + 0] * CIN + c];
            v.y = x[(size_t)sIdx[p][kb * 4 + 1] * CIN + c];
            v.z = x[(size_t)sIdx[p][kb * 4 + 2] * CIN + c];
            v.w = x[(size_t)sIdx[p][kb * 4 + 3] * CIN + c];
            *(float4*)&sXs[p][CD + c][kb * 4] = v;
        }
    }
    // ---- B: h1 = bn1(hardtanh(pd @ W1^T + b1)); sign floats -> sSgnH[p][k][c] ----
    {
        int c = tid & 15, k = tid >> 4;
        float w0 = W1[c * 3 + 0], w1 = W1[c * 3 + 1], w2v = W1[c * 3 + 2];
        float bb = b1[c];
        float s = bn1g[c] * rsqrtf(bn1v[c] + EPSV);
        float tt = bn1b[c] - bn1m[c] * s;
        #pragma unroll
        for (int p = 0; p < PTS; ++p) {
            float z = sPd[p][k * 3 + 0] * w0 + sPd[p][k * 3 + 1] * w1 + sPd[p][k * 3 + 2] * w2v + bb;
            float v = clamp1(z) * s + tt;
            sSgnH[p][k][c] = sgnf(v);
        }
    }
    __syncthreads();

    // ---- C: h2 = bn2(hardtanh(...)) -> sXs rows 0..15 (EXACT r7 chain; float-sign operands) ----
    {
        int c = tid & 15, k = tid >> 4;
        float4 w0 = *(const float4*)&g_w2f[c * 16 + 0];
        float4 w1 = *(const float4*)&g_w2f[c * 16 + 4];
        float4 w2 = *(const float4*)&g_w2f[c * 16 + 8];
        float4 w3 = *(const float4*)&g_w2f[c * 16 + 12];
        float bb = b2[c];
        float s = bn2g[c] * rsqrtf(bn2v[c] + EPSV);
        float tt = bn2b[c] - bn2m[c] * s;
        #pragma unroll
        for (int p = 0; p < PTS; ++p) {
            float4 a0 = *(const float4*)&sSgnH[p][k][0];
            float4 a1 = *(const float4*)&sSgnH[p][k][4];
            float4 a2 = *(const float4*)&sSgnH[p][k][8];
            float4 a3 = *(const float4*)&sSgnH[p][k][12];
            float acc = bb;
            acc += a0.x * w0.x; acc += a0.y * w0.y; acc += a0.z * w0.z; acc += a0.w * w0.w;
            acc += a1.x * w1.x; acc += a1.y * w1.y; acc += a1.z * w1.z; acc += a1.w * w1.w;
            acc += a2.x * w2.x; acc += a2.y * w2.y; acc += a2.z * w2.z; acc += a2.w * w2.w;
            acc += a3.x * w3.x; acc += a3.y * w3.y; acc += a3.z * w3.z; acc += a3.w * w3.w;
            sXs[p][c][k] = clamp1(acc) * s + tt;
        }
    }
    // ---- D: t1 = sign(bn3(hardtanh(pd48 @ Wm^T + bm))) -> sSgn1 floats (exact order) ----
    {
        int j = tid;
        float acc0 = 0.f, acc1 = 0.f, acc2 = 0.f, acc3 = 0.f;
        #pragma unroll 2
        for (int ib = 0; ib < 12; ++ib) {
            float4 w  = *(const float4*)&g_wmt[(ib * 256 + j) * 4];
            float4 q0 = *(const float4*)&sPd[0][ib * 4];
            float4 q1 = *(const float4*)&sPd[1][ib * 4];
            float4 q2 = *(const float4*)&sPd[2][ib * 4];
            float4 q3 = *(const float4*)&sPd[3][ib * 4];
            acc0 += w.x * q0.x; acc1 += w.x * q1.x; acc2 += w.x * q2.x; acc3 += w.x * q3.x;
            acc0 += w.y * q0.y; acc1 += w.y * q1.y; acc2 += w.y * q2.y; acc3 += w.y * q3.y;
            acc0 += w.z * q0.z; acc1 += w.z * q1.z; acc2 += w.z * q2.z; acc3 += w.z * q3.z;
            acc0 += w.w * q0.w; acc1 += w.w * q1.w; acc2 += w.w * q2.w; acc3 += w.w * q3.w;
        }
        float bb = bm[j];
        float s = bn3g[j] * rsqrtf(bn3v[j] + EPSV);
        float tt = bn3b[j] - bn3m[j] * s;
        float vv[PTS] = {acc0, acc1, acc2, acc3};
        #pragma unroll
        for (int p = 0; p < PTS; ++p) {
            float v = clamp1(vv[p] + bb) * s + tt;
            sSgn1[p][j] = sgnf(v);
        }
    }
    __syncthreads();

    // ---- E: t2 = sign(bn4(hardtanh(...))) -> sSgn2 floats (EXACT r7 chain) ----
    {
        int r = tid, c = r >> 4;
        float4 w0 = *(const float4*)&g_cw1f[r * 16 + 0];
        float4 w1 = *(const float4*)&g_cw1f[r * 16 + 4];
        float4 w2 = *(const float4*)&g_cw1f[r * 16 + 8];
        float4 w3 = *(const float4*)&g_cw1f[r * 16 + 12];
        float bb = cb1[r];
        float s = bn4g[r] * rsqrtf(bn4v[r] + EPSV);
        float tt = bn4b[r] - bn4m[r] * s;
        #pragma unroll
        for (int p = 0; p < PTS; ++p) {
            float4 a0 = *(const float4*)&sSgn1[p][c * 16 + 0];
            float4 a1 = *(const float4*)&sSgn1[p][c * 16 + 4];
            float4 a2 = *(const float4*)&sSgn1[p][c * 16 + 8];
            float4 a3 = *(const float4*)&sSgn1[p][c * 16 + 12];
            float acc = bb;
            acc += a0.x * w0.x; acc += a0.y * w0.y; acc += a0.z * w0.z; acc += a0.w * w0.w;
            acc += a1.x * w1.x; acc += a1.y * w1.y; acc += a1.z * w1.z; acc += a1.w * w1.w;
            acc += a2.x * w2.x; acc += a2.y * w2.y; acc += a2.z * w2.z; acc += a2.w * w2.w;
            acc += a3.x * w3.x; acc += a3.y * w3.y; acc += a3.z * w3.z; acc += a3.w * w3.w;
            float v = clamp1(acc) * s + tt;
            sSgn2[p][r] = sgnf(v);
        }
    }
    __syncthreads();

    // ---- F: T = bn5(...) (no hardtanh) -> sT (EXACT r7 chain) ----
    {
        int r = tid, c = r >> 4;
        float4 w0 = *(const float4*)&g_cw2f[r * 16 + 0];
        float4 w1 = *(const float4*)&g_cw2f[r * 16 + 4];
        float4 w2 = *(const float4*)&g_cw2f[r * 16 + 8];
        float4 w3 = *(const float4*)&g_cw2f[r * 16 + 12];
        float bb = cb2[r];
        float s = bn5g[r] * rsqrtf(bn5v[r] + EPSV);
        float tt = bn5b[r] - bn5m[r] * s;
        int i = r >> 4, jj = r & 15;
        #pragma unroll
        for (int p = 0; p < PTS; ++p) {
            float4 a0 = *(const float4*)&sSgn2[p][c * 16 + 0];
            float4 a1 = *(const float4*)&sSgn2[p][c * 16 + 4];
            float4 a2 = *(const float4*)&sSgn2[p][c * 16 + 8];
            float4 a3 = *(const float4*)&sSgn2[p][c * 16 + 12];
            float acc = bb;
            acc += a0.x * w0.x; acc += a0.y * w0.y; acc += a0.z * w0.z; acc += a0.w * w0.w;
            acc += a1.x * w1.x; acc += a1.y * w1.y; acc += a1.z * w1.z; acc += a1.w * w1.w;
            acc += a2.x * w2.x; acc += a2.y * w2.y; acc += a2.z * w2.z; acc += a2.w * w2.w;
            acc += a3.x * w3.x; acc += a3.y * w3.y; acc += a3.z * w3.z; acc += a3.w * w3.w;
            sT[p][i][jj] = acc * s + tt;
        }
    }
    __syncthreads();

    // ---- G: xt[c][i] = sum_j T[i][j]*xs[c][j]; wave=p, lane=(cg,i); unroll-limited ----
    {
        int p = tid >> 6;
        int i = lane & 15, cg = lane >> 4;
        float4 t0 = *(const float4*)&sT[p][i][0];
        float4 t1 = *(const float4*)&sT[p][i][4];
        float4 t2 = *(const float4*)&sT[p][i][8];
        float4 t3 = *(const float4*)&sT[p][i][12];
        #pragma unroll 2
        for (int it = 0; it < 20; ++it) {
            int c = 4 * it + cg;
            float4 r0 = *(const float4*)&sXs[p][c][0];
            float4 r1 = *(const float4*)&sXs[p][c][4];
            float4 r2 = *(const float4*)&sXs[p][c][8];
            float4 r3 = *(const float4*)&sXs[p][c][12];
            float acc = 0.f;
            acc += t0.x * r0.x; acc += t0.y * r0.y; acc += t0.z * r0.z; acc += t0.w * r0.w;
            acc += t1.x * r1.x; acc += t1.y * r1.y; acc += t1.z * r1.z; acc += t1.w * r1.w;
            acc += t2.x * r2.x; acc += t2.y * r2.y; acc += t2.z * r2.z; acc += t2.w * r2.w;
            acc += t3.x * r3.x; acc += t3.y * r3.y; acc += t3.z * r3.z; acc += t3.w * r3.w;
            unsigned long long bp = __ballot(acc > 0.f);
            unsigned long long bn_ = __ballot(acc < 0.f);
            if ((lane & 15) == 0) {
                unsigned sh = lane & 48;
                sPkXt[p][c] = ((unsigned)((bn_ >> sh) & 0xFFFFull) << 16) |
                               (unsigned)((bp >> sh) & 0xFFFFull);
            }
        }
    }
    __syncthreads();

    // ---- H: y = bigconv(sign(xt), cw3) + cb3; ballot-pack sign(y) -> sPkY (tdot-safe) ----
    if (tid < CT * 2) {
        int q = tid, c = q >> 1;
        unsigned wp = g_cw3[0][q], wr = g_cw3[1][q];
        float bb = cb3[q];
        #pragma unroll
        for (int p = 0; p < PTS; ++p) {
            unsigned a = sPkXt[p][c];
            float v = (float)tdot(a, wp, wr) + bb;
            unsigned long long bp = __ballot(v > 0.f);
            unsigned long long bn_ = __ballot(v < 0.f);
            if ((lane & 15) == 0) {
                unsigned sh = lane & 48;
                sPkY[p][q >> 4] = ((unsigned)((bn_ >> sh) & 0xFFFFull) << 16) |
                                   (unsigned)((bp >> sh) & 0xFFFFull);
            }
        }
    }
    __syncthreads();

    // ---- I: out = sign(y) . sign(Wf) + bf (packed; integer-exact; coalesced uint2) ----
    {
        int o = tid & 127, pp = tid >> 7;
        float bb = bf[o];
        unsigned a0[10], a1[10];
        #pragma unroll
        for (int m = 0; m < 10; ++m) { a0[m] = sPkY[2 * pp][m]; a1[m] = sPkY[2 * pp + 1][m]; }
        int acc0 = 0, acc1 = 0;
        #pragma unroll
        for (int m = 0; m < 10; ++m) {
            uint2 w = g_wf2[m * 128 + o];
            acc0 += __popc(a0[m] & w.x) - __popc(a0[m] & w.y);
            acc1 += __popc(a1[m] & w.x) - __popc(a1[m] & w.y);
        }
        out[(size_t)(nb + 2 * pp + 0) * COUT + o] = (float)acc0 + bb;
        out[(size_t)(nb + 2 * pp + 1) * COUT + o] = (float)acc1 + bb;
    }
}

extern "C" void kernel_launch(void* const* d_in, const int* in_sizes, int n_in,
                              void* d_out, int out_size, void* d_ws, size_t ws_size,
                              hipStream_t stream) {
    const float* x    = (const float*)d_in[0];
    const float* pos  = (const float*)d_in[1];
    const int*   col  = (const int*)d_in[2];
    const float* W1   = (const float*)d_in[3];
    const float* b1   = (const float*)d_in[4];
    const float* bn1g = (const float*)d_in[5];
    const float* bn1b = (const float*)d_in[6];
    const float* bn1m = (const float*)d_in[7];
    const float* bn1v = (const float*)d_in[8];
    const float* W2   = (const float*)d_in[9];
    const float* b2   = (const float*)d_in[10];
    const float* bn2g = (const float*)d_in[11];
    const float* bn2b = (const float*)d_in[12];
    const float* bn2m = (const float*)d_in[13];
    const float* bn2v = (const float*)d_in[14];
    const float* Wm   = (const float*)d_in[15];
    const float* bm   = (const float*)d_in[16];
    const float* bn3g = (const float*)d_in[17];
    const float* bn3b = (const float*)d_in[18];
    const float* bn3m = (const float*)d_in[19];
    const float* bn3v = (const float*)d_in[20];
    const float* cw1  = (const float*)d_in[21];
    const float* cb1  = (const float*)d_in[22];
    const float* bn4g = (const float*)d_in[23];
    const float* bn4b = (const float*)d_in[24];
    const float* bn4m = (const float*)d_in[25];
    const float* bn4v = (const float*)d_in[26];
    const float* cw2  = (const float*)d_in[27];
    const float* cb2  = (const float*)d_in[28];
    const float* bn5g = (const float*)d_in[29];
    const float* bn5b = (const float*)d_in[30];
    const float* bn5m = (const float*)d_in[31];
    const float* bn5v = (const float*)d_in[32];
    const float* cw3  = (const float*)d_in[33];
    const float* cb3  = (const float*)d_in[34];
    const float* Wf   = (const float*)d_in[35];
    const float* bf   = (const float*)d_in[36];
    float* outp = (float*)d_out;

    hipLaunchKernelGGL(prep_kernel, dim3(52), dim3(256), 0, stream, Wm, W2, cw1, cw2, cw3, Wf);
    hipLaunchKernelGGL(bixconv_kernel, dim3(NPTS / PTS), dim3(256), 0, stream,
        x, pos, col,
        W1, b1, bn1g, bn1b, bn1m, bn1v,
        b2, bn2g, bn2b, bn2m, bn2v,
        bm, bn3g, bn3b, bn3m, bn3v,
        cb1, bn4g, bn4b, bn4m, bn4v,
        cb2, bn5g, bn5b, bn5m, bn5v,
        cb3, bf, outp);
}

// Round 9
// 291.788 us; speedup vs baseline: 3.1552x; 1.1266x over previous
//
#include <hip/hip_runtime.h>

#define NPTS 100000
#define KN 16
#define DIM 3
#define CIN 64
#define CD 16
#define CT 80
#define COUT 128
#define PTS 4
#define EPSV 1e-5f

// ---- prepacked weights (written by prep_kernel every launch; deterministic) ----
__device__ __align__(16) float g_wmt[48 * 256];  // [(ib*256+j)*4+ii] = Wm[j*48+ib*4+ii]
__device__ __align__(16) float g_w2f[256];       // sign(W2) floats, [c*16+j]
__device__ __align__(16) float g_cw1f[4096];     // sign(cw1) floats, [r*16+k]
__device__ __align__(16) float g_cw2f[4096];     // sign(cw2) floats, [r*16+k]
__device__ unsigned g_cw3[2][160];
__device__ uint2    g_wf2[10 * 128];             // [m*128+o] = {w, rot16(w)}

__device__ __forceinline__ float sgnf(float x) {
    return (x > 0.f) ? 1.f : ((x < 0.f) ? -1.f : 0.f);
}
__device__ __forceinline__ float clamp1(float x) { return fminf(1.f, fmaxf(-1.f, x)); }
__device__ __forceinline__ unsigned rot16(unsigned w) { return (w >> 16) | (w << 16); }

__device__ __forceinline__ unsigned packrow16(const float* __restrict__ w) {
    unsigned pos = 0, neg = 0;
    #pragma unroll
    for (int k = 0; k < 16; ++k) {
        pos |= (w[k] > 0.f ? 1u : 0u) << k;
        neg |= (w[k] < 0.f ? 1u : 0u) << k;
    }
    return (neg << 16) | pos;
}

// ternary dot (integer-exact) — ONLY safe where output feeds sign() of int+bias
__device__ __forceinline__ int tdot(unsigned a, unsigned wp, unsigned wr) {
    return __popc(a & wp) - __popc(a & wr);
}

__global__ void prep_kernel(const float* __restrict__ Wm, const float* __restrict__ W2,
                            const float* __restrict__ cw1, const float* __restrict__ cw2,
                            const float* __restrict__ cw3, const float* __restrict__ Wf) {
    int b = blockIdx.x, t = threadIdx.x;
    if (b < 48) {
        int ib = b >> 2, ii = b & 3;
        g_wmt[(ib * 256 + t) * 4 + ii] = Wm[t * 48 + b];
    } else if (b == 48) {
        #pragma unroll
        for (int k = 0; k < 16; ++k) g_cw1f[t * 16 + k] = sgnf(cw1[t * 16 + k]);
    } else if (b == 49) {
        #pragma unroll
        for (int k = 0; k < 16; ++k) g_cw2f[t * 16 + k] = sgnf(cw2[t * 16 + k]);
    } else if (b == 50) {
        if (t < 160) { unsigned w = packrow16(cw3 + t * 16); g_cw3[0][t] = w; g_cw3[1][t] = rot16(w); }
        else if (t < 176) {
            int c = t - 160;
            #pragma unroll
            for (int j = 0; j < 16; ++j) g_w2f[c * 16 + j] = sgnf(W2[c * 16 + j]);
        }
    } else {
        if (t < 128) {
            for (int m = 0; m < 10; ++m) {
                unsigned w = packrow16(Wf + t * 160 + m * 16);
                g_wf2[m * 128 + t] = make_uint2(w, rot16(w));
            }
        }
    }
}

__global__ __launch_bounds__(256) void bixconv_kernel(
    const float* __restrict__ x, const float* __restrict__ pos, const int* __restrict__ col,
    const float* __restrict__ W1, const float* __restrict__ b1,
    const float* __restrict__ bn1g, const float* __restrict__ bn1b, const float* __restrict__ bn1m, const float* __restrict__ bn1v,
    const float* __restrict__ b2,
    const float* __restrict__ bn2g, const float* __restrict__ bn2b, const float* __restrict__ bn2m, const float* __restrict__ bn2v,
    const float* __restrict__ bm,
    const float* __restrict__ bn3g, const float* __restrict__ bn3b, const float* __restrict__ bn3m, const float* __restrict__ bn3v,
    const float* __restrict__ cb1,
    const float* __restrict__ bn4g, const float* __restrict__ bn4b, const float* __restrict__ bn4m, const float* __restrict__ bn4v,
    const float* __restrict__ cb2,
    const float* __restrict__ bn5g, const float* __restrict__ bn5b, const float* __restrict__ bn5m, const float* __restrict__ bn5v,
    const float* __restrict__ cb3, const float* __restrict__ bf,
    float* __restrict__ out)
{
    // ---- LDS with lifetime-based aliasing (phases separated by __syncthreads) ----
    __shared__ int sIdx[PTS][KN];
    __shared__ __align__(16) float sPd[PTS][48];        // live A1..D; aliased by sPkY (H..I)
    __shared__ __align__(16) float sXs[PTS][CT][20];    // rows 0..15: h2, rows 16..79: x[col]
    __shared__ __align__(16) float sT[PTS][KN][20];     // T (stage F output)
    __shared__ __align__(16) float sSgnHbuf[PTS][256];  // sign(h1) (B..C); aliased by sSgn2 (E..F)
    __shared__ __align__(16) float sSgn1[PTS][256];     // sign(t1) (D..E); aliased by sPkXt (G..H)

    float (*sSgnH)[256]   = sSgnHbuf;                               // [p][k*16+c]
    float (*sSgn2)[256]   = sSgnHbuf;                               // [p][r]
    unsigned (*sPkXt)[CT] = reinterpret_cast<unsigned(*)[CT]>(&sSgn1[0][0]);
    unsigned (*sPkY)[10]  = reinterpret_cast<unsigned(*)[10]>(&sPd[0][0]);

    const int tid = threadIdx.x;
    const int lane = tid & 63;
    const int nb = blockIdx.x * PTS;

    // ---- A1: neighbor indices + relative positions ----
    if (tid < PTS * KN) {
        int p = tid >> 4, k = tid & 15;
        int n = nb + p;
        int idx = col[n * KN + k];
        sIdx[p][k] = idx;
        float ax = pos[n * 3 + 0], ay = pos[n * 3 + 1], az = pos[n * 3 + 2];
        sPd[p][k * 3 + 0] = pos[idx * 3 + 0] - ax;
        sPd[p][k * 3 + 1] = pos[idx * 3 + 1] - ay;
        sPd[p][k * 3 + 2] = pos[idx * 3 + 2] - az;
    }
    __syncthreads();

    // ---- A2: gather x[col] into xs rows 16..79 ----
    {
        int p = tid >> 6, c = lane;
        #pragma unroll
        for (int kb = 0; kb < 4; ++kb) {
            float4 v;
            v.x = x[(size_t)sIdx[p][kb * 4 + 0] * CIN + c];
            v.y = x[(size_t)sIdx[p][kb * 4 + 1] * CIN + c];
            v.z = x[(size_t)sIdx[p][kb * 4 + 2] * CIN + c];
            v.w = x[(size_t)sIdx[p][kb * 4 + 3] * CIN + c];
            *(float4*)&sXs[p][CD + c][kb * 4] = v;
        }
    }
    // ---- B: h1 = bn1(hardtanh(pd @ W1^T + b1)); sign floats -> sSgnH[p][k*16+c] ----
    {
        int c = tid & 15, k = tid >> 4;
        float w0 = W1[c * 3 + 0], w1 = W1[c * 3 + 1], w2v = W1[c * 3 + 2];
        float bb = b1[c];
        float s = bn1g[c] * rsqrtf(bn1v[c] + EPSV);
        float tt = bn1b[c] - bn1m[c] * s;
        #pragma unroll
        for (int p = 0; p < PTS; ++p) {
            float z = sPd[p][k * 3 + 0] * w0 + sPd[p][k * 3 + 1] * w1 + sPd[p][k * 3 + 2] * w2v + bb;
            float v = clamp1(z) * s + tt;
            sSgnH[p][k * 16 + c] = sgnf(v);
        }
    }
    __syncthreads();

    // ---- C: h2 = bn2(hardtanh(...)) -> sXs rows 0..15 (EXACT r8 chain) ----
    {
        int c = tid & 15, k = tid >> 4;
        float4 w0 = *(const float4*)&g_w2f[c * 16 + 0];
        float4 w1 = *(const float4*)&g_w2f[c * 16 + 4];
        float4 w2 = *(const float4*)&g_w2f[c * 16 + 8];
        float4 w3 = *(const float4*)&g_w2f[c * 16 + 12];
        float bb = b2[c];
        float s = bn2g[c] * rsqrtf(bn2v[c] + EPSV);
        float tt = bn2b[c] - bn2m[c] * s;
        #pragma unroll
        for (int p = 0; p < PTS; ++p) {
            float4 a0 = *(const float4*)&sSgnH[p][k * 16 + 0];
            float4 a1 = *(const float4*)&sSgnH[p][k * 16 + 4];
            float4 a2 = *(const float4*)&sSgnH[p][k * 16 + 8];
            float4 a3 = *(const float4*)&sSgnH[p][k * 16 + 12];
            float acc = bb;
            acc += a0.x * w0.x; acc += a0.y * w0.y; acc += a0.z * w0.z; acc += a0.w * w0.w;
            acc += a1.x * w1.x; acc += a1.y * w1.y; acc += a1.z * w1.z; acc += a1.w * w1.w;
            acc += a2.x * w2.x; acc += a2.y * w2.y; acc += a2.z * w2.z; acc += a2.w * w2.w;
            acc += a3.x * w3.x; acc += a3.y * w3.y; acc += a3.z * w3.z; acc += a3.w * w3.w;
            sXs[p][c][k] = clamp1(acc) * s + tt;
        }
    }
    // ---- D: t1 = sign(bn3(hardtanh(pd48 @ Wm^T + bm))) -> sSgn1 floats (exact order) ----
    {
        int j = tid;
        float acc0 = 0.f, acc1 = 0.f, acc2 = 0.f, acc3 = 0.f;
        #pragma unroll 2
        for (int ib = 0; ib < 12; ++ib) {
            float4 w  = *(const float4*)&g_wmt[(ib * 256 + j) * 4];
            float4 q0 = *(const float4*)&sPd[0][ib * 4];
            float4 q1 = *(const float4*)&sPd[1][ib * 4];
            float4 q2 = *(const float4*)&sPd[2][ib * 4];
            float4 q3 = *(const float4*)&sPd[3][ib * 4];
            acc0 += w.x * q0.x; acc1 += w.x * q1.x; acc2 += w.x * q2.x; acc3 += w.x * q3.x;
            acc0 += w.y * q0.y; acc1 += w.y * q1.y; acc2 += w.y * q2.y; acc3 += w.y * q3.y;
            acc0 += w.z * q0.z; acc1 += w.z * q1.z; acc2 += w.z * q2.z; acc3 += w.z * q3.z;
            acc0 += w.w * q0.w; acc1 += w.w * q1.w; acc2 += w.w * q2.w; acc3 += w.w * q3.w;
        }
        float bb = bm[j];
        float s = bn3g[j] * rsqrtf(bn3v[j] + EPSV);
        float tt = bn3b[j] - bn3m[j] * s;
        float vv[PTS] = {acc0, acc1, acc2, acc3};
        #pragma unroll
        for (int p = 0; p < PTS; ++p) {
            float v = clamp1(vv[p] + bb) * s + tt;
            sSgn1[p][j] = sgnf(v);
        }
    }
    __syncthreads();

    // ---- E: t2 = sign(bn4(hardtanh(...))) -> sSgn2 floats (EXACT r8 chain) ----
    {
        int r = tid, c = r >> 4;
        float4 w0 = *(const float4*)&g_cw1f[r * 16 + 0];
        float4 w1 = *(const float4*)&g_cw1f[r * 16 + 4];
        float4 w2 = *(const float4*)&g_cw1f[r * 16 + 8];
        float4 w3 = *(const float4*)&g_cw1f[r * 16 + 12];
        float bb = cb1[r];
        float s = bn4g[r] * rsqrtf(bn4v[r] + EPSV);
        float tt = bn4b[r] - bn4m[r] * s;
        #pragma unroll
        for (int p = 0; p < PTS; ++p) {
            float4 a0 = *(const float4*)&sSgn1[p][c * 16 + 0];
            float4 a1 = *(const float4*)&sSgn1[p][c * 16 + 4];
            float4 a2 = *(const float4*)&sSgn1[p][c * 16 + 8];
            float4 a3 = *(const float4*)&sSgn1[p][c * 16 + 12];
            float acc = bb;
            acc += a0.x * w0.x; acc += a0.y * w0.y; acc += a0.z * w0.z; acc += a0.w * w0.w;
            acc += a1.x * w1.x; acc += a1.y * w1.y; acc += a1.z * w1.z; acc += a1.w * w1.w;
            acc += a2.x * w2.x; acc += a2.y * w2.y; acc += a2.z * w2.z; acc += a2.w * w2.w;
            acc += a3.x * w3.x; acc += a3.y * w3.y; acc += a3.z * w3.z; acc += a3.w * w3.w;
            float v = clamp1(acc) * s + tt;
            sSgn2[p][r] = sgnf(v);
        }
    }
    __syncthreads();

    // ---- F: T = bn5(...) (no hardtanh) -> sT (EXACT r8 chain) ----
    {
        int r = tid, c = r >> 4;
        float4 w0 = *(const float4*)&g_cw2f[r * 16 + 0];
        float4 w1 = *(const float4*)&g_cw2f[r * 16 + 4];
        float4 w2 = *(const float4*)&g_cw2f[r * 16 + 8];
        float4 w3 = *(const float4*)&g_cw2f[r * 16 + 12];
        float bb = cb2[r];
        float s = bn5g[r] * rsqrtf(bn5v[r] + EPSV);
        float tt = bn5b[r] - bn5m[r] * s;
        int i = r >> 4, jj = r & 15;
        #pragma unroll
        for (int p = 0; p < PTS; ++p) {
            float4 a0 = *(const float4*)&sSgn2[p][c * 16 + 0];
            float4 a1 = *(const float4*)&sSgn2[p][c * 16 + 4];
            float4 a2 = *(const float4*)&sSgn2[p][c * 16 + 8];
            float4 a3 = *(const float4*)&sSgn2[p][c * 16 + 12];
            float acc = bb;
            acc += a0.x * w0.x; acc += a0.y * w0.y; acc += a0.z * w0.z; acc += a0.w * w0.w;
            acc += a1.x * w1.x; acc += a1.y * w1.y; acc += a1.z * w1.z; acc += a1.w * w1.w;
            acc += a2.x * w2.x; acc += a2.y * w2.y; acc += a2.z * w2.z; acc += a2.w * w2.w;
            acc += a3.x * w3.x; acc += a3.y * w3.y; acc += a3.z * w3.z; acc += a3.w * w3.w;
            sT[p][i][jj] = acc * s + tt;
        }
    }
    __syncthreads();

    // ---- G: xt[c][i] = sum_j T[i][j]*xs[c][j]; wave=p, lane=(cg,i); unroll-limited ----
    {
        int p = tid >> 6;
        int i = lane & 15, cg = lane >> 4;
        float4 t0 = *(const float4*)&sT[p][i][0];
        float4 t1 = *(const float4*)&sT[p][i][4];
        float4 t2 = *(const float4*)&sT[p][i][8];
        float4 t3 = *(const float4*)&sT[p][i][12];
        #pragma unroll 2
        for (int it = 0; it < 20; ++it) {
            int c = 4 * it + cg;
            float4 r0 = *(const float4*)&sXs[p][c][0];
            float4 r1 = *(const float4*)&sXs[p][c][4];
            float4 r2 = *(const float4*)&sXs[p][c][8];
            float4 r3 = *(const float4*)&sXs[p][c][12];
            float acc = 0.f;
            acc += t0.x * r0.x; acc += t0.y * r0.y; acc += t0.z * r0.z; acc += t0.w * r0.w;
            acc += t1.x * r1.x; acc += t1.y * r1.y; acc += t1.z * r1.z; acc += t1.w * r1.w;
            acc += t2.x * r2.x; acc += t2.y * r2.y; acc += t2.z * r2.z; acc += t2.w * r2.w;
            acc += t3.x * r3.x; acc += t3.y * r3.y; acc += t3.z * r3.z; acc += t3.w * r3.w;
            unsigned long long bp = __ballot(acc > 0.f);
            unsigned long long bn_ = __ballot(acc < 0.f);
            if ((lane & 15) == 0) {
                unsigned sh = lane & 48;
                sPkXt[p][c] = ((unsigned)((bn_ >> sh) & 0xFFFFull) << 16) |
                               (unsigned)((bp >> sh) & 0xFFFFull);
            }
        }
    }
    __syncthreads();

    // ---- H: y = bigconv(sign(xt), cw3) + cb3; ballot-pack sign(y) -> sPkY (tdot-safe) ----
    if (tid < CT * 2) {
        int q = tid, c = q >> 1;
        unsigned wp = g_cw3[0][q], wr = g_cw3[1][q];
        float bb = cb3[q];
        #pragma unroll
        for (int p = 0; p < PTS; ++p) {
            unsigned a = sPkXt[p][c];
            float v = (float)tdot(a, wp, wr) + bb;
            unsigned long long bp = __ballot(v > 0.f);
            unsigned long long bn_ = __ballot(v < 0.f);
            if ((lane & 15) == 0) {
                unsigned sh = lane & 48;
                sPkY[p][q >> 4] = ((unsigned)((bn_ >> sh) & 0xFFFFull) << 16) |
                                   (unsigned)((bp >> sh) & 0xFFFFull);
            }
        }
    }
    __syncthreads();

    // ---- I: out = sign(y) . sign(Wf) + bf (packed; integer-exact; coalesced uint2) ----
    {
        int o = tid & 127, pp = tid >> 7;
        float bb = bf[o];
        unsigned a0[10], a1[10];
        #pragma unroll
        for (int m = 0; m < 10; ++m) { a0[m] = sPkY[2 * pp][m]; a1[m] = sPkY[2 * pp + 1][m]; }
        int acc0 = 0, acc1 = 0;
        #pragma unroll
        for (int m = 0; m < 10; ++m) {
            uint2 w = g_wf2[m * 128 + o];
            acc0 += __popc(a0[m] & w.x) - __popc(a0[m] & w.y);
            acc1 += __popc(a1[m] & w.x) - __popc(a1[m] & w.y);
        }
        out[(size_t)(nb + 2 * pp + 0) * COUT + o] = (float)acc0 + bb;
        out[(size_t)(nb + 2 * pp + 1) * COUT + o] = (float)acc1 + bb;
    }
}

extern "C" void kernel_launch(void* const* d_in, const int* in_sizes, int n_in,
                              void* d_out, int out_size, void* d_ws, size_t ws_size,
                              hipStream_t stream) {
    const float* x    = (const float*)d_in[0];
    const float* pos  = (const float*)d_in[1];
    const int*   col  = (const int*)d_in[2];
    const float* W1   = (const float*)d_in[3];
    const float* b1   = (const float*)d_in[4];
    const float* bn1g = (const float*)d_in[5];
    const float* bn1b = (const float*)d_in[6];
    const float* bn1m = (const float*)d_in[7];
    const float* bn1v = (const float*)d_in[8];
    const float* W2   = (const float*)d_in[9];
    const float* b2   = (const float*)d_in[10];
    const float* bn2g = (const float*)d_in[11];
    const float* bn2b = (const float*)d_in[12];
    const float* bn2m = (const float*)d_in[13];
    const float* bn2v = (const float*)d_in[14];
    const float* Wm   = (const float*)d_in[15];
    const float* bm   = (const float*)d_in[16];
    const float* bn3g = (const float*)d_in[17];
    const float* bn3b = (const float*)d_in[18];
    const float* bn3m = (const float*)d_in[19];
    const float* bn3v = (const float*)d_in[20];
    const float* cw1  = (const float*)d_in[21];
    const float* cb1  = (const float*)d_in[22];
    const float* bn4g = (const float*)d_in[23];
    const float* bn4b = (const float*)d_in[24];
    const float* bn4m = (const float*)d_in[25];
    const float* bn4v = (const float*)d_in[26];
    const float* cw2  = (const float*)d_in[27];
    const float* cb2  = (const float*)d_in[28];
    const float* bn5g = (const float*)d_in[29];
    const float* bn5b = (const float*)d_in[30];
    const float* bn5m = (const float*)d_in[31];
    const float* bn5v = (const float*)d_in[32];
    const float* cw3  = (const float*)d_in[33];
    const float* cb3  = (const float*)d_in[34];
    const float* Wf   = (const float*)d_in[35];
    const float* bf   = (const float*)d_in[36];
    float* outp = (float*)d_out;

    hipLaunchKernelGGL(prep_kernel, dim3(52), dim3(256), 0, stream, Wm, W2, cw1, cw2, cw3, Wf);
    hipLaunchKernelGGL(bixconv_kernel, dim3(NPTS / PTS), dim3(256), 0, stream,
        x, pos, col,
        W1, b1, bn1g, bn1b, bn1m, bn1v,
        b2, bn2g, bn2b, bn2m, bn2v,
        bm, bn3g, bn3b, bn3m, bn3v,
        cb1, bn4g, bn4b, bn4m, bn4v,
        cb2, bn5g, bn5b, bn5m, bn5v,
        cb3, bf, outp);
}